// Round 3
// baseline (348.448 us; speedup 1.0000x reference)
//
#include <hip/hip_runtime.h>
#include <stdint.h>

#define Bn 4
#define Cn 256
#define Gn 32
#define Nn 4096
#define CGn 8

typedef unsigned short u16;
typedef __attribute__((ext_vector_type(8))) short short8;
typedef __attribute__((ext_vector_type(4))) short short4v;
typedef __attribute__((ext_vector_type(4))) float f32x4;

__device__ __forceinline__ u16 f2bf(float x) {
  uint32_t u = __float_as_uint(x);
  u += 0x7fffu + ((u >> 16) & 1u);
  return (u16)(u >> 16);
}
__device__ __forceinline__ float b2f(u16 v) {
  return __uint_as_float(((uint32_t)v) << 16);
}

// async global->LDS, 16B per lane; lds base must be wave-uniform
__device__ __forceinline__ void gl_lds16(const void* g, void* l) {
  __builtin_amdgcn_global_load_lds(
      (__attribute__((address_space(1))) void*)(uintptr_t)g,
      (__attribute__((address_space(3))) void*)(uintptr_t)l, 16, 0, 0);
}

// XOR-swizzled tile addressing: rows of 512B (32 x 16B chunks) / 128B (8 chunks).
__device__ __forceinline__ int sw512(int row, int cb) { return row * 512 + ((cb ^ (row & 7)) * 16); }
__device__ __forceinline__ int sw128(int row, int cb) { return row * 128 + ((cb ^ (row & 7)) * 16); }

// ---------------- weight convert: fp32 -> bf16, fold log2(e)/16 into wq,bq ----
// also zeroes the GN stats accumulators (k_stats uses atomicAdd)
__global__ void k_conv(const float* __restrict__ wq, const float* __restrict__ wk,
                       const float* __restrict__ wv, const float* __restrict__ wp,
                       const float* __restrict__ bq, const float* __restrict__ bk,
                       const float* __restrict__ bv,
                       u16* __restrict__ wqkv, u16* __restrict__ wpb, float* __restrict__ bqkv,
                       float* __restrict__ stats) {
  const float s = 0.09016844005556021f;  // log2(e) / sqrt(256)
  int i = blockIdx.x * 256 + threadIdx.x;  // grid 256 -> 65536 threads
  wqkv[i]          = f2bf(wq[i] * s);
  wqkv[i + 65536]  = f2bf(wk[i]);
  wqkv[i + 131072] = f2bf(wv[i]);
  wpb[i]           = f2bf(wp[i]);
  if (i < 256) { bqkv[i] = bq[i] * s; bqkv[i + 256] = bk[i]; bqkv[i + 512] = bv[i]; }
  if (blockIdx.x == 0 && threadIdx.x < 256) stats[threadIdx.x] = 0.f;
}

// ---------------- GroupNorm stats: 4 blocks per (b,g), atomic accumulate -----
__global__ void k_stats(const float* __restrict__ x, float* __restrict__ stats) {
  int blk = blockIdx.x;           // (b*32+g)*4 + part
  int grp = blk >> 2, part = blk & 3;
  const float4* base = (const float4*)(x + (size_t)grp * (CGn * Nn) + part * 8192);
  float s = 0.f, s2 = 0.f;
  for (int i = threadIdx.x; i < 2048; i += 256) {
    float4 v = base[i];
    s  += v.x + v.y + v.z + v.w;
    s2 += v.x * v.x + v.y * v.y + v.z * v.z + v.w * v.w;
  }
#pragma unroll
  for (int m = 1; m < 64; m <<= 1) { s += __shfl_xor(s, m, 64); s2 += __shfl_xor(s2, m, 64); }
  __shared__ float ps[4], ps2[4];
  int w = threadIdx.x >> 6;
  if ((threadIdx.x & 63) == 0) { ps[w] = s; ps2[w] = s2; }
  __syncthreads();
  if (threadIdx.x == 0) {
    atomicAdd(&stats[grp * 2], ps[0] + ps[1] + ps[2] + ps[3]);
    atomicAdd(&stats[grp * 2 + 1], ps2[0] + ps2[1] + ps2[2] + ps2[3]);
  }
}

// ---------------- GN apply -> hnT (N,C) bf16 ---------------------------------
__global__ void k_apply(const float* __restrict__ x, const float* __restrict__ stats,
                        const float* __restrict__ gsc, const float* __restrict__ gbi,
                        u16* __restrict__ hnT) {
  int n0 = blockIdx.x * 64;
  int b = blockIdx.y;
  int tid = threadIdx.x;
  __shared__ float smu[Gn], srs[Gn];
  if (tid < Gn) {
    float S = stats[(b * Gn + tid) * 2], S2 = stats[(b * Gn + tid) * 2 + 1];
    const float inv = 1.f / (CGn * Nn);
    float mu = S * inv;
    float var = S2 * inv - mu * mu;
    smu[tid] = mu;
    srs[tid] = rsqrtf(var + 1e-6f);
  }
  __syncthreads();
  int nl = (tid & 15) * 4;
  int cbase = tid >> 4;
  for (int pass = 0; pass < 16; ++pass) {
    int c = pass * 16 + cbase;
    float4 v = *(const float4*)(x + (size_t)b * Cn * Nn + (size_t)c * Nn + n0 + nl);
    int g = c >> 3;
    float sc = gsc[c] * srs[g];
    float bi = gbi[c] - smu[g] * sc;
    u16* dst = hnT + (size_t)b * Nn * Cn + (size_t)(n0 + nl) * Cn + c;
    dst[0]      = f2bf(v.x * sc + bi);
    dst[Cn]     = f2bf(v.y * sc + bi);
    dst[2 * Cn] = f2bf(v.z * sc + bi);
    dst[3 * Cn] = f2bf(v.w * sc + bi);
  }
}

// ---------------- fused QKV GEMM: out[d,n] = sum_c W[d,c] hn[c,n] + bias ------
// q,k stored transposed (N,C); v stored (C,N); coalesced stores via LDS transpose
__global__ __launch_bounds__(256, 2)
void k_qkv(const u16* __restrict__ wqkv, const float* __restrict__ bqkv,
           const u16* __restrict__ hnT, u16* __restrict__ qT, u16* __restrict__ kT,
           u16* __restrict__ vv) {
  __shared__ __align__(16) char smem[65536];  // Ws [64][512B sw] | hns [64][512B sw]
  int tid = threadIdx.x, lane = tid & 63, w = tid >> 6, quad = lane >> 4, low = lane & 15;
  int n0 = blockIdx.x * 64, d0 = blockIdx.y * 64, b = blockIdx.z;
  {
    int r0 = w * 16;
#pragma unroll
    for (int s = 0; s < 8; ++s) {
      int rs = r0 + s * 2;
      int r = rs + (lane >> 5);
      int cb = (lane & 31) ^ (r & 7);
      gl_lds16(wqkv + (size_t)(d0 + r) * Cn + cb * 8, smem + rs * 512);
      gl_lds16(hnT + ((size_t)b * Nn + n0 + r) * Cn + cb * 8, smem + 32768 + rs * 512);
    }
  }
  asm volatile("s_waitcnt vmcnt(0)" ::: "memory");
  __syncthreads();
  f32x4 acc[4] = {{0.f,0.f,0.f,0.f},{0.f,0.f,0.f,0.f},{0.f,0.f,0.f,0.f},{0.f,0.f,0.f,0.f}};
#pragma unroll
  for (int kk = 0; kk < 8; ++kk) {
    short8 af = *(const short8*)(smem + sw512(w * 16 + low, kk * 4 + quad));
#pragma unroll
    for (int t = 0; t < 4; ++t) {
      short8 bf = *(const short8*)(smem + 32768 + sw512(t * 16 + low, kk * 4 + quad));
      acc[t] = __builtin_amdgcn_mfma_f32_16x16x32_bf16(af, bf, acc[t], 0, 0, 0);
    }
  }
  int which = d0 >> 8;
  float bias[4];
#pragma unroll
  for (int r = 0; r < 4; ++r) bias[r] = bqkv[d0 + w * 16 + quad * 4 + r];
  __syncthreads();  // all waves done reading GEMM tiles; reuse smem[0..8K)
  if (which == 2) {
    // v tile in (d_local-major) layout: 64 rows x 128B, hash (row>>1)&7
#pragma unroll
    for (int t = 0; t < 4; ++t)
#pragma unroll
      for (int r = 0; r < 4; ++r) {
        int row = w * 16 + quad * 4 + r;   // d_local
        int col = t * 16 + low;            // n_local
        int off = row * 128 + ((((col >> 3) ^ ((row >> 1) & 7)) & 7) * 16) + (col & 7) * 2;
        *(u16*)(smem + off) = f2bf(acc[t][r] + bias[r]);
      }
  } else {
    // q/k tile in (n_local-major) layout: 64 rows x 128B
#pragma unroll
    for (int t = 0; t < 4; ++t)
#pragma unroll
      for (int r = 0; r < 4; ++r) {
        int row = t * 16 + low;            // n_local
        int col = w * 16 + quad * 4 + r;   // d_local
        int off = row * 128 + ((((col >> 3) ^ ((row >> 1) & 7)) & 7) * 16) + (col & 7) * 2;
        *(u16*)(smem + off) = f2bf(acc[t][r] + bias[r]);
      }
  }
  __syncthreads();
  int dl0 = d0 & 255;
#pragma unroll
  for (int p = 0; p < 2; ++p) {
    int idx = p * 256 + tid;       // [0,512) chunk-slots
    int row = idx >> 3, pc = idx & 7;
    int cb = pc ^ ((row >> 1) & 7);
    short8 v8 = *(const short8*)(smem + row * 128 + pc * 16);
    if (which == 2)
      *(short8*)(vv + (size_t)b * Cn * Nn + (size_t)(dl0 + row) * Nn + n0 + cb * 8) = v8;
    else {
      u16* dst = (which == 0 ? qT : kT) + (size_t)b * Nn * Cn;
      *(short8*)(dst + (size_t)(n0 + row) * Cn + dl0 + cb * 8) = v8;
    }
  }
}

// ---------------- flash attention: 128 q-rows x 8 waves, 4-way KV split -------
// fixed-max (m=0) log2-domain softmax: logits bounded by construction, so no
// online rescale; partials combine linearly as (sum O_p) / (sum l_p)
__global__ __launch_bounds__(512, 4)
void k_flash(const u16* __restrict__ qT, const u16* __restrict__ kT,
             const u16* __restrict__ vv, u16* __restrict__ Op0,
             u16* __restrict__ Op1, u16* __restrict__ Op2, u16* __restrict__ Op3,
             float* __restrict__ lrow) {
  __shared__ __align__(16) char smem[65536];  // ks [64][512B sw] | vs [256][128B sw]
  const int tid = threadIdx.x, lane = tid & 63, w = tid >> 6, quad = lane >> 4, low = lane & 15;
  const int i0 = blockIdx.x * 128;
  const int b = blockIdx.y;
  const int jh = blockIdx.z;  // 0..3
  const u16* qTb = qT + (size_t)b * Nn * Cn;
  const u16* kTb = kT + (size_t)b * Nn * Cn;
  const u16* vb  = vv + (size_t)b * Cn * Nn;

  // q A-fragments for this wave's 16 rows (full K=256) in registers
  short8 qf[8];
  {
    const u16* qrow = qTb + (size_t)(i0 + w * 16 + low) * Cn;
#pragma unroll
    for (int kk = 0; kk < 8; ++kk) qf[kk] = *(const short8*)(qrow + kk * 32 + quad * 8);
  }
  f32x4 O[16];
#pragma unroll
  for (int t = 0; t < 16; ++t) O[t] = (f32x4){0.f, 0.f, 0.f, 0.f};
  float l_[4] = {0.f, 0.f, 0.f, 0.f};  // per-lane partial row sums

  for (int jt = 0; jt < 16; ++jt) {
    const int j0 = jh * 1024 + jt * 64;
    __syncthreads();  // everyone done reading prev ks/vs/P
#pragma unroll
    for (int s = 0; s < 4; ++s) {  // ks: wave w stages rows w*8 .. +8
      int rs = w * 8 + s * 2;
      int r = rs + (lane >> 5);
      int cb = (lane & 31) ^ (r & 7);
      gl_lds16(kTb + (size_t)(j0 + r) * Cn + cb * 8, smem + rs * 512);
    }
#pragma unroll
    for (int s = 0; s < 4; ++s) {  // vs: wave w stages channel rows w*32 .. +32
      int rs = w * 32 + s * 8;
      int r = rs + (lane >> 3);
      int cb = (lane & 7) ^ (r & 7);
      gl_lds16(vb + (size_t)r * Nn + j0 + cb * 8, smem + 32768 + rs * 128);
    }
    asm volatile("s_waitcnt vmcnt(0)" ::: "memory");
    __syncthreads();

    // S = q^T k (wave: 16 rows x 64 cols, log2-domain logits)
    f32x4 S4[4] = {{0.f,0.f,0.f,0.f},{0.f,0.f,0.f,0.f},{0.f,0.f,0.f,0.f},{0.f,0.f,0.f,0.f}};
#pragma unroll
    for (int kk = 0; kk < 8; ++kk)
#pragma unroll
      for (int t = 0; t < 4; ++t) {
        short8 bf = *(const short8*)(smem + sw512(t * 16 + low, kk * 4 + quad));
        S4[t] = __builtin_amdgcn_mfma_f32_16x16x32_bf16(qf[kk], bf, S4[t], 0, 0, 0);
      }
    __syncthreads();  // all waves done reading ks; reuse ks region for P

    // P = exp2(S); per-lane l accumulation (no max, no rescale)
    float Pv[4][4];
#pragma unroll
    for (int t = 0; t < 4; ++t)
#pragma unroll
      for (int r = 0; r < 4; ++r) {
        float p = __builtin_amdgcn_exp2f(S4[t][r]);
        Pv[t][r] = p;
        l_[r] += p;
      }
    // write P (16 x 64 bf16) to wave's 2KB slot in the ks region
#pragma unroll
    for (int t = 0; t < 4; ++t)
#pragma unroll
      for (int r = 0; r < 4; ++r) {
        int mrow = quad * 4 + r;
        int col = t * 16 + low;
        int off = w * 2048 + mrow * 128 + ((((col >> 3) ^ ((mrow >> 1) & 7)) & 7) * 16) + (col & 7) * 2;
        *(u16*)(smem + off) = f2bf(Pv[t][r]);
      }
    // O += P @ V^T
#pragma unroll
    for (int kk2 = 0; kk2 < 2; ++kk2) {
      short8 af = *(const short8*)(smem + w * 2048 + low * 128 +
                                   ((((kk2 * 4 + quad) ^ ((low >> 1) & 7)) & 7) * 16));
#pragma unroll
      for (int t = 0; t < 16; ++t) {
        short8 bf = *(const short8*)(smem + 32768 + sw128(t * 16 + low, kk2 * 4 + quad));
        O[t] = __builtin_amdgcn_mfma_f32_16x16x32_bf16(af, bf, O[t], 0, 0, 0);
      }
    }
  }

  // reduce per-lane l over the 16 low lanes -> full row sums
#pragma unroll
  for (int r = 0; r < 4; ++r) {
    float s0 = l_[r];
#pragma unroll
    for (int msk = 1; msk < 16; msk <<= 1) s0 += __shfl_xor(s0, msk, 64);
    l_[r] = s0;
  }
  if (low == 0) {
#pragma unroll
    for (int r = 0; r < 4; ++r)
      lrow[(size_t)jh * (Bn * Nn) + (size_t)b * Nn + i0 + w * 16 + quad * 4 + r] = l_[r];
  }
  __syncthreads();  // ks/vs dead; reuse all 64KB for the O transpose
#pragma unroll
  for (int t = 0; t < 16; ++t)
#pragma unroll
    for (int r = 0; r < 4; ++r) {
      int row = quad * 4 + r;       // local q-row within wave
      int col = t * 16 + low;       // channel
      int off = w * 8192 + row * 512 + (((col >> 3) ^ ((row >> 1) & 7)) * 16) + (col & 7) * 2;
      *(u16*)(smem + off) = f2bf(O[t][r]);
    }
  __syncthreads();
  u16* Opj = (jh == 0) ? Op0 : (jh == 1) ? Op1 : (jh == 2) ? Op2 : Op3;
  u16* Ob = Opj + ((size_t)b * Nn + i0 + w * 16) * (size_t)Cn;
#pragma unroll
  for (int s = 0; s < 8; ++s) {
    int r = s * 2 + (lane >> 5);
    int pc = lane & 31;
    int cb = pc ^ ((r >> 1) & 7);
    short8 v8 = *(const short8*)(smem + w * 8192 + r * 512 + pc * 16);
    *(short8*)(Ob + (size_t)r * Cn + cb * 8) = v8;
  }
}

// ---------------- combine the 4 KV partials -> OT (N,C) bf16 -----------------
__global__ void k_comb(const u16* __restrict__ O0, const u16* __restrict__ O1,
                       const u16* __restrict__ O2, const u16* __restrict__ O3,
                       const float* __restrict__ lrow, u16* __restrict__ OT) {
  int gid = blockIdx.x * 256 + threadIdx.x;  // 1M threads, 4 cols each
  int row = gid >> 6;
  int c4 = (gid & 63) << 2;
  float L = lrow[row] + lrow[Bn * Nn + row] + lrow[2 * Bn * Nn + row] + lrow[3 * Bn * Nn + row];
  float inv = __builtin_amdgcn_rcpf(L);
  size_t base = (size_t)row * Cn + c4;
  short4v a0 = *(const short4v*)(O0 + base);
  short4v a1 = *(const short4v*)(O1 + base);
  short4v a2 = *(const short4v*)(O2 + base);
  short4v a3 = *(const short4v*)(O3 + base);
  short4v o;
#pragma unroll
  for (int i = 0; i < 4; ++i)
    o[i] = (short)f2bf((b2f((u16)a0[i]) + b2f((u16)a1[i]) + b2f((u16)a2[i]) + b2f((u16)a3[i])) * inv);
  *(short4v*)(OT + base) = o;
}

// ---------------- proj GEMM + bias + residual --------------------------------
__global__ __launch_bounds__(256, 2)
void k_proj(const u16* __restrict__ wpb, const float* __restrict__ bp,
            const u16* __restrict__ OT, const float* __restrict__ x,
            float* __restrict__ out) {
  __shared__ __align__(16) char smem[65536];
  int tid = threadIdx.x, lane = tid & 63, w = tid >> 6, quad = lane >> 4, low = lane & 15;
  int n0 = blockIdx.x * 64, d0 = blockIdx.y * 64, b = blockIdx.z;
  {
    int r0 = w * 16;
#pragma unroll
    for (int s = 0; s < 8; ++s) {
      int rs = r0 + s * 2;
      int r = rs + (lane >> 5);
      int cb = (lane & 31) ^ (r & 7);
      gl_lds16(wpb + (size_t)(d0 + r) * Cn + cb * 8, smem + rs * 512);
      gl_lds16(OT + ((size_t)b * Nn + n0 + r) * Cn + cb * 8, smem + 32768 + rs * 512);
    }
  }
  asm volatile("s_waitcnt vmcnt(0)" ::: "memory");
  __syncthreads();
  f32x4 acc[4] = {{0.f,0.f,0.f,0.f},{0.f,0.f,0.f,0.f},{0.f,0.f,0.f,0.f},{0.f,0.f,0.f,0.f}};
#pragma unroll
  for (int kk = 0; kk < 8; ++kk) {
    short8 af = *(const short8*)(smem + sw512(w * 16 + low, kk * 4 + quad));
#pragma unroll
    for (int t = 0; t < 4; ++t) {
      short8 bf = *(const short8*)(smem + 32768 + sw512(t * 16 + low, kk * 4 + quad));
      acc[t] = __builtin_amdgcn_mfma_f32_16x16x32_bf16(af, bf, acc[t], 0, 0, 0);
    }
  }
  int dloc = d0 + w * 16 + quad * 4;
#pragma unroll
  for (int t = 0; t < 4; ++t)
#pragma unroll
    for (int r = 0; r < 4; ++r) {
      size_t idx = (size_t)b * Cn * Nn + (size_t)(dloc + r) * Nn + n0 + t * 16 + low;
      out[idx] = x[idx] + acc[t][r] + bp[dloc + r];
    }
}

// ---------------- launcher ----------------------------------------------------
extern "C" void kernel_launch(void* const* d_in, const int* in_sizes, int n_in,
                              void* d_out, int out_size, void* d_ws, size_t ws_size,
                              hipStream_t stream) {
  const float* x   = (const float*)d_in[0];
  const float* gsc = (const float*)d_in[1];
  const float* gbi = (const float*)d_in[2];
  const float* wq  = (const float*)d_in[3];
  const float* bq  = (const float*)d_in[4];
  const float* wk  = (const float*)d_in[5];
  const float* bk  = (const float*)d_in[6];
  const float* wv  = (const float*)d_in[7];
  const float* bv  = (const float*)d_in[8];
  const float* wp  = (const float*)d_in[9];
  const float* bp  = (const float*)d_in[10];
  float* out = (float*)d_out;

  char* ws = (char*)d_ws;
  u16*   wqkv  = (u16*)(ws + 0);          // 384 KB
  u16*   wpb   = (u16*)(ws + 393216);     // 128 KB
  float* bqkv  = (float*)(ws + 524288);   // 3 KB
  float* stats = (float*)(ws + 527360);   // 1 KB (zeroed by k_conv)
  float* lrow  = (float*)(ws + 528384);   // 4*16384*4 = 256 KB
  u16*   hnT   = (u16*)(ws + 1048576);    // 8 MB; reused as Op0 after qkv
  u16*   qT    = (u16*)(ws + 9437184);    // 8 MB; reused as OT after flash
  u16*   kT    = (u16*)(ws + 17825792);   // 8 MB
  u16*   vv    = (u16*)(ws + 26214400);   // 8 MB
  u16*   Op1   = (u16*)(ws + 34603008);   // 8 MB
  u16*   Op2   = (u16*)(ws + 42991616);   // 8 MB
  u16*   Op3   = (u16*)(ws + 51380224);   // 8 MB; end ~57 MB

  k_conv<<<256, 256, 0, stream>>>(wq, wk, wv, wp, bq, bk, bv, wqkv, wpb, bqkv, stats);
  k_stats<<<512, 256, 0, stream>>>(x, stats);
  k_apply<<<dim3(64, 4), 256, 0, stream>>>(x, stats, gsc, gbi, hnT);
  k_qkv<<<dim3(64, 12, 4), 256, 0, stream>>>(wqkv, bqkv, hnT, qT, kT, vv);
  k_flash<<<dim3(32, 4, 4), 512, 0, stream>>>(qT, kT, vv, hnT /*Op0*/, Op1, Op2, Op3, lrow);
  k_comb<<<4096, 256, 0, stream>>>(hnT, Op1, Op2, Op3, lrow, qT /*OT*/);
  k_proj<<<dim3(64, 4, 4), 256, 0, stream>>>(wpb, bp, qT /*OT*/, x, out);
}

// Round 4
// 281.864 us; speedup vs baseline: 1.2362x; 1.2362x over previous
//
#include <hip/hip_runtime.h>
#include <stdint.h>

#define Bn 4
#define Cn 256
#define Gn 32
#define Nn 4096
#define CGn 8

typedef unsigned short u16;
typedef __attribute__((ext_vector_type(8))) short short8;
typedef __attribute__((ext_vector_type(4))) short short4v;
typedef __attribute__((ext_vector_type(4))) float f32x4;
typedef __attribute__((ext_vector_type(16))) float f32x16;

__device__ __forceinline__ u16 f2bf(float x) {
  uint32_t u = __float_as_uint(x);
  u += 0x7fffu + ((u >> 16) & 1u);
  return (u16)(u >> 16);
}
__device__ __forceinline__ float b2f(u16 v) {
  return __uint_as_float(((uint32_t)v) << 16);
}

// async global->LDS, 16B per lane; lds base must be wave-uniform
__device__ __forceinline__ void gl_lds16(const void* g, void* l) {
  __builtin_amdgcn_global_load_lds(
      (__attribute__((address_space(1))) void*)(uintptr_t)g,
      (__attribute__((address_space(3))) void*)(uintptr_t)l, 16, 0, 0);
}

// XOR-swizzled tile addressing (qkv/proj GEMMs): rows of 512B (32 x 16B chunks)
__device__ __forceinline__ int sw512(int row, int cb) { return row * 512 + ((cb ^ (row & 7)) * 16); }

// ---------------- weight convert: fp32 -> bf16, fold log2(e)/16 into wq,bq ----
__global__ void k_conv(const float* __restrict__ wq, const float* __restrict__ wk,
                       const float* __restrict__ wv, const float* __restrict__ wp,
                       const float* __restrict__ bq, const float* __restrict__ bk,
                       const float* __restrict__ bv,
                       u16* __restrict__ wqkv, u16* __restrict__ wpb, float* __restrict__ bqkv,
                       float* __restrict__ stats) {
  const float s = 0.09016844005556021f;  // log2(e) / sqrt(256)
  int i = blockIdx.x * 256 + threadIdx.x;  // grid 256 -> 65536 threads
  wqkv[i]          = f2bf(wq[i] * s);
  wqkv[i + 65536]  = f2bf(wk[i]);
  wqkv[i + 131072] = f2bf(wv[i]);
  wpb[i]           = f2bf(wp[i]);
  if (i < 256) { bqkv[i] = bq[i] * s; bqkv[i + 256] = bk[i]; bqkv[i + 512] = bv[i]; }
  if (blockIdx.x == 0 && threadIdx.x < 256) stats[threadIdx.x] = 0.f;
}

// ---------------- GroupNorm stats: 4 blocks per (b,g), atomic accumulate -----
__global__ void k_stats(const float* __restrict__ x, float* __restrict__ stats) {
  int blk = blockIdx.x;           // (b*32+g)*4 + part
  int grp = blk >> 2, part = blk & 3;
  const float4* base = (const float4*)(x + (size_t)grp * (CGn * Nn) + part * 8192);
  float s = 0.f, s2 = 0.f;
  for (int i = threadIdx.x; i < 2048; i += 256) {
    float4 v = base[i];
    s  += v.x + v.y + v.z + v.w;
    s2 += v.x * v.x + v.y * v.y + v.z * v.z + v.w * v.w;
  }
#pragma unroll
  for (int m = 1; m < 64; m <<= 1) { s += __shfl_xor(s, m, 64); s2 += __shfl_xor(s2, m, 64); }
  __shared__ float ps[4], ps2[4];
  int w = threadIdx.x >> 6;
  if ((threadIdx.x & 63) == 0) { ps[w] = s; ps2[w] = s2; }
  __syncthreads();
  if (threadIdx.x == 0) {
    atomicAdd(&stats[grp * 2], ps[0] + ps[1] + ps[2] + ps[3]);
    atomicAdd(&stats[grp * 2 + 1], ps2[0] + ps2[1] + ps2[2] + ps2[3]);
  }
}

// ---------------- GN apply -> hnT (N,C) bf16 ---------------------------------
__global__ void k_apply(const float* __restrict__ x, const float* __restrict__ stats,
                        const float* __restrict__ gsc, const float* __restrict__ gbi,
                        u16* __restrict__ hnT) {
  int n0 = blockIdx.x * 64;
  int b = blockIdx.y;
  int tid = threadIdx.x;
  __shared__ float smu[Gn], srs[Gn];
  if (tid < Gn) {
    float S = stats[(b * Gn + tid) * 2], S2 = stats[(b * Gn + tid) * 2 + 1];
    const float inv = 1.f / (CGn * Nn);
    float mu = S * inv;
    float var = S2 * inv - mu * mu;
    smu[tid] = mu;
    srs[tid] = rsqrtf(var + 1e-6f);
  }
  __syncthreads();
  int nl = (tid & 15) * 4;
  int cbase = tid >> 4;
  for (int pass = 0; pass < 16; ++pass) {
    int c = pass * 16 + cbase;
    float4 v = *(const float4*)(x + (size_t)b * Cn * Nn + (size_t)c * Nn + n0 + nl);
    int g = c >> 3;
    float sc = gsc[c] * srs[g];
    float bi = gbi[c] - smu[g] * sc;
    u16* dst = hnT + (size_t)b * Nn * Cn + (size_t)(n0 + nl) * Cn + c;
    dst[0]      = f2bf(v.x * sc + bi);
    dst[Cn]     = f2bf(v.y * sc + bi);
    dst[2 * Cn] = f2bf(v.z * sc + bi);
    dst[3 * Cn] = f2bf(v.w * sc + bi);
  }
}

// ---------------- fused QKV GEMM: out[d,n] = sum_c W[d,c] hn[c,n] + bias ------
// q,k stored transposed (N,C); v stored (C,N); coalesced stores via LDS transpose
__global__ __launch_bounds__(256, 2)
void k_qkv(const u16* __restrict__ wqkv, const float* __restrict__ bqkv,
           const u16* __restrict__ hnT, u16* __restrict__ qT, u16* __restrict__ kT,
           u16* __restrict__ vv) {
  __shared__ __align__(16) char smem[65536];  // Ws [64][512B sw] | hns [64][512B sw]
  int tid = threadIdx.x, lane = tid & 63, w = tid >> 6, quad = lane >> 4, low = lane & 15;
  int n0 = blockIdx.x * 64, d0 = blockIdx.y * 64, b = blockIdx.z;
  {
    int r0 = w * 16;
#pragma unroll
    for (int s = 0; s < 8; ++s) {
      int rs = r0 + s * 2;
      int r = rs + (lane >> 5);
      int cb = (lane & 31) ^ (r & 7);
      gl_lds16(wqkv + (size_t)(d0 + r) * Cn + cb * 8, smem + rs * 512);
      gl_lds16(hnT + ((size_t)b * Nn + n0 + r) * Cn + cb * 8, smem + 32768 + rs * 512);
    }
  }
  asm volatile("s_waitcnt vmcnt(0)" ::: "memory");
  __syncthreads();
  f32x4 acc[4] = {{0.f,0.f,0.f,0.f},{0.f,0.f,0.f,0.f},{0.f,0.f,0.f,0.f},{0.f,0.f,0.f,0.f}};
#pragma unroll
  for (int kk = 0; kk < 8; ++kk) {
    short8 af = *(const short8*)(smem + sw512(w * 16 + low, kk * 4 + quad));
#pragma unroll
    for (int t = 0; t < 4; ++t) {
      short8 bf = *(const short8*)(smem + 32768 + sw512(t * 16 + low, kk * 4 + quad));
      acc[t] = __builtin_amdgcn_mfma_f32_16x16x32_bf16(af, bf, acc[t], 0, 0, 0);
    }
  }
  int which = d0 >> 8;
  float bias[4];
#pragma unroll
  for (int r = 0; r < 4; ++r) bias[r] = bqkv[d0 + w * 16 + quad * 4 + r];
  __syncthreads();  // all waves done reading GEMM tiles; reuse smem[0..8K)
  if (which == 2) {
#pragma unroll
    for (int t = 0; t < 4; ++t)
#pragma unroll
      for (int r = 0; r < 4; ++r) {
        int row = w * 16 + quad * 4 + r;   // d_local
        int col = t * 16 + low;            // n_local
        int off = row * 128 + ((((col >> 3) ^ ((row >> 1) & 7)) & 7) * 16) + (col & 7) * 2;
        *(u16*)(smem + off) = f2bf(acc[t][r] + bias[r]);
      }
  } else {
#pragma unroll
    for (int t = 0; t < 4; ++t)
#pragma unroll
      for (int r = 0; r < 4; ++r) {
        int row = t * 16 + low;            // n_local
        int col = w * 16 + quad * 4 + r;   // d_local
        int off = row * 128 + ((((col >> 3) ^ ((row >> 1) & 7)) & 7) * 16) + (col & 7) * 2;
        *(u16*)(smem + off) = f2bf(acc[t][r] + bias[r]);
      }
  }
  __syncthreads();
  int dl0 = d0 & 255;
#pragma unroll
  for (int p = 0; p < 2; ++p) {
    int idx = p * 256 + tid;       // [0,512) chunk-slots
    int row = idx >> 3, pc = idx & 7;
    int cb = pc ^ ((row >> 1) & 7);
    short8 v8 = *(const short8*)(smem + row * 128 + pc * 16);
    if (which == 2)
      *(short8*)(vv + (size_t)b * Cn * Nn + (size_t)(dl0 + row) * Nn + n0 + cb * 8) = v8;
    else {
      u16* dst = (which == 0 ? qT : kT) + (size_t)b * Nn * Cn;
      *(short8*)(dst + (size_t)(n0 + row) * Cn + dl0 + cb * 8) = v8;
    }
  }
}

// ---------------- flash attention: M=32/wave via operand-swapped 32x32x16 ----
// Block: 4 waves x 32 q-rows = 128 q, KV split 4-way (blockIdx.z), j-tile 64.
// S^T = K·q  (A = K-tile from LDS, B = q regs); P stays in registers and feeds
// PV (O^T[c][i] = V·P) after one shfl_xor(32) half-exchange. Fixed-max (m=0)
// log2-domain softmax. LDS: ks 64x512B | vs 256x128B, ADD-rotated chunks.
__global__ __launch_bounds__(256, 2)
void k_flash(const u16* __restrict__ qT, const u16* __restrict__ kT,
             const u16* __restrict__ vv, u16* __restrict__ Op0,
             u16* __restrict__ Op1, u16* __restrict__ Op2, u16* __restrict__ Op3,
             float* __restrict__ lrow) {
  __shared__ __align__(16) char smem[65536];
  const int tid = threadIdx.x, lane = tid & 63, w = tid >> 6;
  const int lo = lane & 31, hi = lane >> 5;
  const int i0 = blockIdx.x * 128;
  const int b = blockIdx.y, jh = blockIdx.z;
  const u16* qTb = qT + (size_t)b * Nn * Cn;
  const u16* kTb = kT + (size_t)b * Nn * Cn;
  const u16* vb  = vv + (size_t)b * Cn * Nn;

  // q B-frags: lane holds q[i = i0+w*32+lo][c = ks*16 + hi*8 + e], e=0..7
  short8 qf[16];
  {
    const u16* qrow = qTb + (size_t)(i0 + w * 32 + lo) * Cn + hi * 8;
#pragma unroll
    for (int ks = 0; ks < 16; ++ks) qf[ks] = *(const short8*)(qrow + ks * 16);
  }
  f32x16 Oa[8];
#pragma unroll
  for (int ct = 0; ct < 8; ++ct)
#pragma unroll
    for (int e = 0; e < 16; ++e) Oa[ct][e] = 0.f;
  float l_ = 0.f;
  const int u7 = lo + hi;            // read-rotation helper
  const int krow = w * 16 + hi;      // ks staging: this lane's row for call s: +2s
  const int vrow = w * 64 + (lane >> 3);  // vs staging row: +8s
  const int vp = lane & 7;

  for (int jt = 0; jt < 16; ++jt) {
    const int j0 = jh * 1024 + jt * 64;
    __syncthreads();
    // stage ks: rows pre-rotated so LDS chunk p of row j holds global chunk (p-j)&31
#pragma unroll
    for (int s = 0; s < 8; ++s) {
      int j = krow + s * 2;
      int gc = (lo - j) & 31;
      gl_lds16(kTb + (size_t)(j0 + j) * Cn + gc * 8, smem + (w * 16 + s * 2) * 512);
    }
#pragma unroll
    for (int s = 0; s < 8; ++s) {
      int c = vrow + s * 8;
      int gc = (vp - c) & 7;
      gl_lds16(vb + (size_t)c * Nn + j0 + gc * 8, smem + 32768 + (w * 64 + s * 8) * 128);
    }
    asm volatile("s_waitcnt vmcnt(0)" ::: "memory");
    __syncthreads();

    // S^T tiles: D[m=j][n=i], A = ks rows (rotated), B = qf
    f32x16 S0, S1;
#pragma unroll
    for (int e = 0; e < 16; ++e) { S0[e] = 0.f; S1[e] = 0.f; }
#pragma unroll
    for (int ks = 0; ks < 16; ++ks) {
      int ch = (ks * 2 + u7) & 31;
      short8 a0 = *(const short8*)(smem + lo * 512 + ch * 16);
      short8 a1 = *(const short8*)(smem + (32 + lo) * 512 + ch * 16);
      S0 = __builtin_amdgcn_mfma_f32_32x32x16_bf16(a0, qf[ks], S0, 0, 0, 0);
      S1 = __builtin_amdgcn_mfma_f32_32x32x16_bf16(a1, qf[ks], S1, 0, 0, 0);
    }

    // P = exp2(S); pack to bf16 pairs; accumulate l per-lane (fixed max m=0)
    uint32_t Pp[2][8];
#pragma unroll
    for (int g = 0; g < 8; ++g) {
      float p0 = __builtin_amdgcn_exp2f(S0[2 * g]);
      float p1 = __builtin_amdgcn_exp2f(S0[2 * g + 1]);
      float p2 = __builtin_amdgcn_exp2f(S1[2 * g]);
      float p3 = __builtin_amdgcn_exp2f(S1[2 * g + 1]);
      l_ += (p0 + p1) + (p2 + p3);
      Pp[0][g] = ((uint32_t)f2bf(p1) << 16) | f2bf(p0);
      Pp[1][g] = ((uint32_t)f2bf(p3) << 16) | f2bf(p2);
    }

    // PV: D[m=c][n=i] += V·P ; P B-frag needs the partner half-lane's values
#pragma unroll
    for (int kst = 0; kst < 4; ++kst) {
      int k1 = kst & 1, T = kst >> 1;
      uint32_t a0 = Pp[T][4 * k1], a1 = Pp[T][4 * k1 + 1];
      uint32_t b0 = Pp[T][4 * k1 + 2], b1 = Pp[T][4 * k1 + 3];
      uint32_t s0 = hi ? a0 : b0, s1 = hi ? a1 : b1;
      uint32_t r0 = (uint32_t)__shfl_xor((int)s0, 32, 64);
      uint32_t r1 = (uint32_t)__shfl_xor((int)s1, 32, 64);
      union { uint32_t u[4]; short8 s8; } pu;
      pu.u[0] = hi ? r0 : a0;
      pu.u[1] = hi ? r1 : a1;
      pu.u[2] = hi ? b0 : r0;
      pu.u[3] = hi ? b1 : r1;
      int ch = (kst * 2 + u7) & 7;
#pragma unroll
      for (int ct = 0; ct < 8; ++ct) {
        short8 vf = *(const short8*)(smem + 32768 + (ct * 32 + lo) * 128 + ch * 16);
        Oa[ct] = __builtin_amdgcn_mfma_f32_32x32x16_bf16(vf, pu.s8, Oa[ct], 0, 0, 0);
      }
    }
  }

  // full row-sum l (lane pair holds complementary j halves)
  l_ += __shfl_xor(l_, 32, 64);
  if (hi == 0)
    lrow[(size_t)jh * (Bn * Nn) + (size_t)b * Nn + i0 + w * 32 + lo] = l_;
  float invl = __builtin_amdgcn_rcpf(l_);
  __syncthreads();  // everyone done with ks/vs; reuse all 64KB for O transpose
  // O^T C-layout -> (i-row, c-contig) rows in wave-private 16KB, ADD-rotated
#pragma unroll
  for (int ct = 0; ct < 8; ++ct)
#pragma unroll
    for (int g = 0; g < 4; ++g) {
      short4v pk;
#pragma unroll
      for (int r = 0; r < 4; ++r) pk[r] = (short)f2bf(Oa[ct][g * 4 + r] * invl);
      int chv = (ct * 4 + g + lo) & 31;
      *(short4v*)(smem + w * 16384 + lo * 512 + chv * 16 + hi * 8) = pk;
    }
  u16* Opj = (jh == 0) ? Op0 : (jh == 1) ? Op1 : (jh == 2) ? Op2 : Op3;
  u16* Ob = Opj + ((size_t)b * Nn + i0 + w * 32) * (size_t)Cn;
#pragma unroll
  for (int s = 0; s < 16; ++s) {
    int rr = s * 2 + hi;
    short8 v8 = *(const short8*)(smem + w * 16384 + rr * 512 + lo * 16);
    int gc = (lo - rr) & 31;
    *(short8*)(Ob + (size_t)rr * Cn + gc * 8) = v8;
  }
}

// ---------------- combine the 4 KV partials -> OT (N,C) bf16 -----------------
__global__ void k_comb(const u16* __restrict__ O0, const u16* __restrict__ O1,
                       const u16* __restrict__ O2, const u16* __restrict__ O3,
                       const float* __restrict__ lrow, u16* __restrict__ OT) {
  int gid = blockIdx.x * 256 + threadIdx.x;  // 1M threads, 4 cols each
  int row = gid >> 6;
  int c4 = (gid & 63) << 2;
  float L = lrow[row] + lrow[Bn * Nn + row] + lrow[2 * Bn * Nn + row] + lrow[3 * Bn * Nn + row];
  float inv = __builtin_amdgcn_rcpf(L);
  size_t base = (size_t)row * Cn + c4;
  short4v a0 = *(const short4v*)(O0 + base);
  short4v a1 = *(const short4v*)(O1 + base);
  short4v a2 = *(const short4v*)(O2 + base);
  short4v a3 = *(const short4v*)(O3 + base);
  short4v o;
#pragma unroll
  for (int i = 0; i < 4; ++i)
    o[i] = (short)f2bf((b2f((u16)a0[i]) + b2f((u16)a1[i]) + b2f((u16)a2[i]) + b2f((u16)a3[i])) * inv);
  *(short4v*)(OT + base) = o;
}

// ---------------- proj GEMM + bias + residual --------------------------------
__global__ __launch_bounds__(256, 2)
void k_proj(const u16* __restrict__ wpb, const float* __restrict__ bp,
            const u16* __restrict__ OT, const float* __restrict__ x,
            float* __restrict__ out) {
  __shared__ __align__(16) char smem[65536];
  int tid = threadIdx.x, lane = tid & 63, w = tid >> 6, quad = lane >> 4, low = lane & 15;
  int n0 = blockIdx.x * 64, d0 = blockIdx.y * 64, b = blockIdx.z;
  {
    int r0 = w * 16;
#pragma unroll
    for (int s = 0; s < 8; ++s) {
      int rs = r0 + s * 2;
      int r = rs + (lane >> 5);
      int cb = (lane & 31) ^ (r & 7);
      gl_lds16(wpb + (size_t)(d0 + r) * Cn + cb * 8, smem + rs * 512);
      gl_lds16(OT + ((size_t)b * Nn + n0 + r) * Cn + cb * 8, smem + 32768 + rs * 512);
    }
  }
  asm volatile("s_waitcnt vmcnt(0)" ::: "memory");
  __syncthreads();
  f32x4 acc[4] = {{0.f,0.f,0.f,0.f},{0.f,0.f,0.f,0.f},{0.f,0.f,0.f,0.f},{0.f,0.f,0.f,0.f}};
#pragma unroll
  for (int kk = 0; kk < 8; ++kk) {
    short8 af = *(const short8*)(smem + sw512(w * 16 + low, kk * 4 + quad));
#pragma unroll
    for (int t = 0; t < 4; ++t) {
      short8 bf = *(const short8*)(smem + 32768 + sw512(t * 16 + low, kk * 4 + quad));
      acc[t] = __builtin_amdgcn_mfma_f32_16x16x32_bf16(af, bf, acc[t], 0, 0, 0);
    }
  }
  int dloc = d0 + w * 16 + quad * 4;
#pragma unroll
  for (int t = 0; t < 4; ++t)
#pragma unroll
    for (int r = 0; r < 4; ++r) {
      size_t idx = (size_t)b * Cn * Nn + (size_t)(dloc + r) * Nn + n0 + t * 16 + low;
      out[idx] = x[idx] + acc[t][r] + bp[dloc + r];
    }
}

// ---------------- launcher ----------------------------------------------------
extern "C" void kernel_launch(void* const* d_in, const int* in_sizes, int n_in,
                              void* d_out, int out_size, void* d_ws, size_t ws_size,
                              hipStream_t stream) {
  const float* x   = (const float*)d_in[0];
  const float* gsc = (const float*)d_in[1];
  const float* gbi = (const float*)d_in[2];
  const float* wq  = (const float*)d_in[3];
  const float* bq  = (const float*)d_in[4];
  const float* wk  = (const float*)d_in[5];
  const float* bk  = (const float*)d_in[6];
  const float* wv  = (const float*)d_in[7];
  const float* bv  = (const float*)d_in[8];
  const float* wp  = (const float*)d_in[9];
  const float* bp  = (const float*)d_in[10];
  float* out = (float*)d_out;

  char* ws = (char*)d_ws;
  u16*   wqkv  = (u16*)(ws + 0);          // 384 KB
  u16*   wpb   = (u16*)(ws + 393216);     // 128 KB
  float* bqkv  = (float*)(ws + 524288);   // 3 KB
  float* stats = (float*)(ws + 527360);   // 1 KB (zeroed by k_conv)
  float* lrow  = (float*)(ws + 528384);   // 256 KB
  u16*   hnT   = (u16*)(ws + 1048576);    // 8 MB; reused as Op0 after qkv
  u16*   qT    = (u16*)(ws + 9437184);    // 8 MB; reused as OT after flash
  u16*   kT    = (u16*)(ws + 17825792);   // 8 MB
  u16*   vv    = (u16*)(ws + 26214400);   // 8 MB
  u16*   Op1   = (u16*)(ws + 34603008);   // 8 MB
  u16*   Op2   = (u16*)(ws + 42991616);   // 8 MB
  u16*   Op3   = (u16*)(ws + 51380224);   // 8 MB; end ~57 MB

  k_conv<<<256, 256, 0, stream>>>(wq, wk, wv, wp, bq, bk, bv, wqkv, wpb, bqkv, stats);
  k_stats<<<512, 256, 0, stream>>>(x, stats);
  k_apply<<<dim3(64, 4), 256, 0, stream>>>(x, stats, gsc, gbi, hnT);
  k_qkv<<<dim3(64, 12, 4), 256, 0, stream>>>(wqkv, bqkv, hnT, qT, kT, vv);
  k_flash<<<dim3(32, 4, 4), 256, 0, stream>>>(qT, kT, vv, hnT /*Op0*/, Op1, Op2, Op3, lrow);
  k_comb<<<4096, 256, 0, stream>>>(hnT, Op1, Op2, Op3, lrow, qT /*OT*/);
  k_proj<<<dim3(64, 4, 4), 256, 0, stream>>>(wpb, bp, qT /*OT*/, x, out);
}

// Round 5
// 205.833 us; speedup vs baseline: 1.6929x; 1.3694x over previous
//
#include <hip/hip_runtime.h>
#include <stdint.h>

#define Bn 4
#define Cn 256
#define Gn 32
#define Nn 4096
#define CGn 8

typedef unsigned short u16;
typedef __attribute__((ext_vector_type(8))) short short8;
typedef __attribute__((ext_vector_type(4))) short short4v;
typedef __attribute__((ext_vector_type(4))) float f32x4;
typedef __attribute__((ext_vector_type(16))) float f32x16;

__device__ __forceinline__ u16 f2bf(float x) {
  uint32_t u = __float_as_uint(x);
  u += 0x7fffu + ((u >> 16) & 1u);
  return (u16)(u >> 16);
}
__device__ __forceinline__ float b2f(u16 v) {
  return __uint_as_float(((uint32_t)v) << 16);
}

// async global->LDS, 16B per lane; lds base must be wave-uniform
__device__ __forceinline__ void gl_lds16(const void* g, void* l) {
  __builtin_amdgcn_global_load_lds(
      (__attribute__((address_space(1))) void*)(uintptr_t)g,
      (__attribute__((address_space(3))) void*)(uintptr_t)l, 16, 0, 0);
}

// XOR-swizzled tile addressing (qkv/proj GEMMs): rows of 512B (32 x 16B chunks)
__device__ __forceinline__ int sw512(int row, int cb) { return row * 512 + ((cb ^ (row & 7)) * 16); }

// ---------------- fused weight-convert + GN stats ----------------------------
// blocks 0..255: fp32->bf16 weights (fold log2(e)/16 into wq,bq)
// blocks 256..767: GN partial sums, non-atomic per-part slots stats[grp][part][2]
__global__ void k_cs(const float* __restrict__ wq, const float* __restrict__ wk,
                     const float* __restrict__ wv, const float* __restrict__ wp,
                     const float* __restrict__ bq, const float* __restrict__ bk,
                     const float* __restrict__ bv, const float* __restrict__ x,
                     u16* __restrict__ wqkv, u16* __restrict__ wpb,
                     float* __restrict__ bqkv, float* __restrict__ stats) {
  if (blockIdx.x < 256) {
    const float s = 0.09016844005556021f;  // log2(e) / sqrt(256)
    int i = blockIdx.x * 256 + threadIdx.x;
    wqkv[i]          = f2bf(wq[i] * s);
    wqkv[i + 65536]  = f2bf(wk[i]);
    wqkv[i + 131072] = f2bf(wv[i]);
    wpb[i]           = f2bf(wp[i]);
    if (i < 256) { bqkv[i] = bq[i] * s; bqkv[i + 256] = bk[i]; bqkv[i + 512] = bv[i]; }
  } else {
    int blk = blockIdx.x - 256;     // (b*32+g)*4 + part
    int grp = blk >> 2, part = blk & 3;
    const float4* base = (const float4*)(x + (size_t)grp * (CGn * Nn) + part * 8192);
    float s = 0.f, s2 = 0.f;
    for (int i = threadIdx.x; i < 2048; i += 256) {
      float4 v = base[i];
      s  += v.x + v.y + v.z + v.w;
      s2 += v.x * v.x + v.y * v.y + v.z * v.z + v.w * v.w;
    }
#pragma unroll
    for (int m = 1; m < 64; m <<= 1) { s += __shfl_xor(s, m, 64); s2 += __shfl_xor(s2, m, 64); }
    __shared__ float ps[4], ps2[4];
    int w = threadIdx.x >> 6;
    if ((threadIdx.x & 63) == 0) { ps[w] = s; ps2[w] = s2; }
    __syncthreads();
    if (threadIdx.x == 0) {
      stats[grp * 8 + part * 2]     = ps[0] + ps[1] + ps[2] + ps[3];
      stats[grp * 8 + part * 2 + 1] = ps2[0] + ps2[1] + ps2[2] + ps2[3];
    }
  }
}

// ---------------- GN apply -> hnT (N,C) bf16, coalesced via LDS transpose ----
__global__ void k_apply(const float* __restrict__ x, const float* __restrict__ stats,
                        const float* __restrict__ gsc, const float* __restrict__ gbi,
                        u16* __restrict__ hnT) {
  __shared__ __align__(16) char smem[32768];  // 64 n-rows x 512B (c), rotated
  __shared__ float smu[Gn], srs[Gn];
  int n0 = blockIdx.x * 64;
  int b = blockIdx.y;
  int tid = threadIdx.x;
  if (tid < Gn) {
    float S = 0.f, S2 = 0.f;
#pragma unroll
    for (int p = 0; p < 4; ++p) {
      S  += stats[(b * Gn + tid) * 8 + p * 2];
      S2 += stats[(b * Gn + tid) * 8 + p * 2 + 1];
    }
    const float inv = 1.f / (CGn * Nn);
    float mu = S * inv;
    float var = S2 * inv - mu * mu;
    smu[tid] = mu;
    srs[tid] = rsqrtf(var + 1e-6f);
  }
  __syncthreads();
  int nl = (tid & 15) * 4;
  int cbase = tid >> 4;
  for (int pass = 0; pass < 16; ++pass) {
    int c = pass * 16 + cbase;
    float4 v = *(const float4*)(x + (size_t)b * Cn * Nn + (size_t)c * Nn + n0 + nl);
    int g = c >> 3;
    float sc = gsc[c] * srs[g];
    float bi = gbi[c] - smu[g] * sc;
    float vals[4] = {v.x, v.y, v.z, v.w};
#pragma unroll
    for (int i = 0; i < 4; ++i) {
      int row = nl + i;
      int off = row * 512 + ((((c >> 3) + row) & 31) * 16) + (c & 7) * 2;
      *(u16*)(smem + off) = f2bf(vals[i] * sc + bi);
    }
  }
  __syncthreads();
#pragma unroll
  for (int p = 0; p < 8; ++p) {
    int idx = p * 256 + tid;   // 2048 chunk-slots
    int row = idx >> 5, pc = idx & 31;
    int gc = (pc - row) & 31;
    short8 v8 = *(const short8*)(smem + row * 512 + pc * 16);
    *(short8*)(hnT + ((size_t)b * Nn + n0 + row) * Cn + gc * 8) = v8;
  }
}

// ---------------- fused QKV GEMM: out[d,n] = sum_c W[d,c] hn[c,n] + bias ------
// q,k stored transposed (N,C); v stored (C,N); coalesced stores via LDS transpose
__global__ __launch_bounds__(256, 2)
void k_qkv(const u16* __restrict__ wqkv, const float* __restrict__ bqkv,
           const u16* __restrict__ hnT, u16* __restrict__ qT, u16* __restrict__ kT,
           u16* __restrict__ vv) {
  __shared__ __align__(16) char smem[65536];  // Ws [64][512B sw] | hns [64][512B sw]
  int tid = threadIdx.x, lane = tid & 63, w = tid >> 6, quad = lane >> 4, low = lane & 15;
  int n0 = blockIdx.x * 64, d0 = blockIdx.y * 64, b = blockIdx.z;
  {
    int r0 = w * 16;
#pragma unroll
    for (int s = 0; s < 8; ++s) {
      int rs = r0 + s * 2;
      int r = rs + (lane >> 5);
      int cb = (lane & 31) ^ (r & 7);
      gl_lds16(wqkv + (size_t)(d0 + r) * Cn + cb * 8, smem + rs * 512);
      gl_lds16(hnT + ((size_t)b * Nn + n0 + r) * Cn + cb * 8, smem + 32768 + rs * 512);
    }
  }
  asm volatile("s_waitcnt vmcnt(0)" ::: "memory");
  __syncthreads();
  f32x4 acc[4] = {{0.f,0.f,0.f,0.f},{0.f,0.f,0.f,0.f},{0.f,0.f,0.f,0.f},{0.f,0.f,0.f,0.f}};
#pragma unroll
  for (int kk = 0; kk < 8; ++kk) {
    short8 af = *(const short8*)(smem + sw512(w * 16 + low, kk * 4 + quad));
#pragma unroll
    for (int t = 0; t < 4; ++t) {
      short8 bf = *(const short8*)(smem + 32768 + sw512(t * 16 + low, kk * 4 + quad));
      acc[t] = __builtin_amdgcn_mfma_f32_16x16x32_bf16(af, bf, acc[t], 0, 0, 0);
    }
  }
  int which = d0 >> 8;
  float bias[4];
#pragma unroll
  for (int r = 0; r < 4; ++r) bias[r] = bqkv[d0 + w * 16 + quad * 4 + r];
  __syncthreads();  // all waves done reading GEMM tiles; reuse smem[0..8K)
  if (which == 2) {
#pragma unroll
    for (int t = 0; t < 4; ++t)
#pragma unroll
      for (int r = 0; r < 4; ++r) {
        int row = w * 16 + quad * 4 + r;   // d_local
        int col = t * 16 + low;            // n_local
        int off = row * 128 + ((((col >> 3) ^ ((row >> 1) & 7)) & 7) * 16) + (col & 7) * 2;
        *(u16*)(smem + off) = f2bf(acc[t][r] + bias[r]);
      }
  } else {
#pragma unroll
    for (int t = 0; t < 4; ++t)
#pragma unroll
      for (int r = 0; r < 4; ++r) {
        int row = t * 16 + low;            // n_local
        int col = w * 16 + quad * 4 + r;   // d_local
        int off = row * 128 + ((((col >> 3) ^ ((row >> 1) & 7)) & 7) * 16) + (col & 7) * 2;
        *(u16*)(smem + off) = f2bf(acc[t][r] + bias[r]);
      }
  }
  __syncthreads();
  int dl0 = d0 & 255;
#pragma unroll
  for (int p = 0; p < 2; ++p) {
    int idx = p * 256 + tid;       // [0,512) chunk-slots
    int row = idx >> 3, pc = idx & 7;
    int cb = pc ^ ((row >> 1) & 7);
    short8 v8 = *(const short8*)(smem + row * 128 + pc * 16);
    if (which == 2)
      *(short8*)(vv + (size_t)b * Cn * Nn + (size_t)(dl0 + row) * Nn + n0 + cb * 8) = v8;
    else {
      u16* dst = (which == 0 ? qT : kT) + (size_t)b * Nn * Cn;
      *(short8*)(dst + (size_t)(n0 + row) * Cn + dl0 + cb * 8) = v8;
    }
  }
}

// ---------------- flash attention, pipelined double-buffered K-loop ----------
// 4 waves x 32 q-rows = 128 q/block; KV split 4-way; j-tile 32, dbuf 2x32KB.
// Loads for tile t+1 issued before compute(t); s_waitcnt vmcnt(8) + raw
// s_barrier (no vmcnt(0) drain in the loop). Fixed-max (m=0) log2 softmax.
__device__ __forceinline__ void flash_stage(char* smem, int bsel, const u16* kTb,
                                            const u16* vb, int j0, int w, int lo,
                                            int kr, int vr, int vp) {
  char* ksb = smem + bsel * 32768;
  char* vsb = ksb + 16384;
#pragma unroll
  for (int s = 0; s < 4; ++s) {   // ks: 32 rows x 512B, row-rotated chunks
    int j = kr + s * 2;
    int gc = (lo - j) & 31;
    gl_lds16(kTb + (size_t)(j0 + j) * Cn + gc * 8, ksb + (w * 8 + s * 2) * 512);
  }
#pragma unroll
  for (int s = 0; s < 4; ++s) {   // vs: 256 rows x 64B, row-rotated chunks
    int c = vr + s * 16;
    int gc = (vp - c) & 3;
    gl_lds16(vb + (size_t)c * Nn + j0 + gc * 8, vsb + (w * 64 + s * 16) * 64);
  }
}

__global__ __launch_bounds__(256, 2)
void k_flash(const u16* __restrict__ qT, const u16* __restrict__ kT,
             const u16* __restrict__ vv, u16* __restrict__ Op0,
             u16* __restrict__ Op1, u16* __restrict__ Op2, u16* __restrict__ Op3,
             float* __restrict__ lrow) {
  __shared__ __align__(16) char smem[65536];
  const int tid = threadIdx.x, lane = tid & 63, w = tid >> 6;
  const int lo = lane & 31, hi = lane >> 5;
  const int i0 = blockIdx.x * 128;
  const int b = blockIdx.y, jh = blockIdx.z;
  const u16* qTb = qT + (size_t)b * Nn * Cn;
  const u16* kTb = kT + (size_t)b * Nn * Cn;
  const u16* vb  = vv + (size_t)b * Cn * Nn;
  const int u7 = lo + hi;
  const int kr = w * 8 + hi;
  const int vr = w * 64 + (lane >> 2);
  const int vp = lane & 3;

  flash_stage(smem, 0, kTb, vb, jh * 1024, w, lo, kr, vr, vp);

  // q B-frags: lane holds q[i = i0+w*32+lo][c = ks*16 + hi*8 + e]
  short8 qf[16];
  {
    const u16* qrow = qTb + (size_t)(i0 + w * 32 + lo) * Cn + hi * 8;
#pragma unroll
    for (int ks = 0; ks < 16; ++ks) qf[ks] = *(const short8*)(qrow + ks * 16);
  }
  f32x16 Oa[8];
#pragma unroll
  for (int ct = 0; ct < 8; ++ct)
#pragma unroll
    for (int e = 0; e < 16; ++e) Oa[ct][e] = 0.f;
  float l_ = 0.f;

  for (int jt = 0; jt < 32; ++jt) {
    if (jt < 31) {
      flash_stage(smem, (jt + 1) & 1, kTb, vb, jh * 1024 + (jt + 1) * 32, w, lo, kr, vr, vp);
      asm volatile("s_waitcnt vmcnt(8)" ::: "memory");   // only the older 8 (current tile)
    } else {
      asm volatile("s_waitcnt vmcnt(0)" ::: "memory");
    }
    asm volatile("s_barrier" ::: "memory");              // raw: no vmcnt(0) drain
    const char* ksb = smem + (jt & 1) * 32768;
    const char* vsb = ksb + 16384;

    // S^T = K·q : D[m=j 32][n=i 32], A = ks (rotated), B = qf
    f32x16 S0;
#pragma unroll
    for (int e = 0; e < 16; ++e) S0[e] = 0.f;
#pragma unroll
    for (int ks = 0; ks < 16; ++ks) {
      int ch = (ks * 2 + u7) & 31;
      short8 a0 = *(const short8*)(ksb + lo * 512 + ch * 16);
      S0 = __builtin_amdgcn_mfma_f32_32x32x16_bf16(a0, qf[ks], S0, 0, 0, 0);
    }
    // P = exp2(S), pack bf16 pairs, per-lane l
    uint32_t Pp[8];
#pragma unroll
    for (int g = 0; g < 8; ++g) {
      float p0 = __builtin_amdgcn_exp2f(S0[2 * g]);
      float p1 = __builtin_amdgcn_exp2f(S0[2 * g + 1]);
      l_ += p0 + p1;
      Pp[g] = ((uint32_t)f2bf(p1) << 16) | f2bf(p0);
    }
    // PV: O^T[m=c][n=i] += V·P ; P B-frag via half-lane exchange
#pragma unroll
    for (int kst = 0; kst < 2; ++kst) {
      uint32_t a0 = Pp[4 * kst], a1 = Pp[4 * kst + 1];
      uint32_t b0 = Pp[4 * kst + 2], b1 = Pp[4 * kst + 3];
      uint32_t s0 = hi ? a0 : b0, s1 = hi ? a1 : b1;
      uint32_t r0 = (uint32_t)__shfl_xor((int)s0, 32, 64);
      uint32_t r1 = (uint32_t)__shfl_xor((int)s1, 32, 64);
      union { uint32_t u[4]; short8 s8; } pu;
      pu.u[0] = hi ? r0 : a0;
      pu.u[1] = hi ? r1 : a1;
      pu.u[2] = hi ? b0 : r0;
      pu.u[3] = hi ? b1 : r1;
      int ch = (kst * 2 + u7) & 3;
#pragma unroll
      for (int ct = 0; ct < 8; ++ct) {
        short8 vf = *(const short8*)(vsb + (ct * 32 + lo) * 64 + ch * 16);
        Oa[ct] = __builtin_amdgcn_mfma_f32_32x32x16_bf16(vf, pu.s8, Oa[ct], 0, 0, 0);
      }
    }
    asm volatile("s_barrier" ::: "memory");              // readers done before restage
  }

  // l: lane pair holds complementary j halves
  l_ += __shfl_xor(l_, 32, 64);
  if (hi == 0)
    lrow[(size_t)jh * (Bn * Nn) + (size_t)b * Nn + i0 + w * 32 + lo] = l_;
  float invl = __builtin_amdgcn_rcpf(l_);
  __syncthreads();  // loop drained (vmcnt(0) at last iter); reuse all 64KB
#pragma unroll
  for (int ct = 0; ct < 8; ++ct)
#pragma unroll
    for (int g = 0; g < 4; ++g) {
      short4v pk;
#pragma unroll
      for (int r = 0; r < 4; ++r) pk[r] = (short)f2bf(Oa[ct][g * 4 + r] * invl);
      int chv = (ct * 4 + g + lo) & 31;
      *(short4v*)(smem + w * 16384 + lo * 512 + chv * 16 + hi * 8) = pk;
    }
  __syncthreads();
  u16* Opj = (jh == 0) ? Op0 : (jh == 1) ? Op1 : (jh == 2) ? Op2 : Op3;
  u16* Ob = Opj + ((size_t)b * Nn + i0 + w * 32) * (size_t)Cn;
#pragma unroll
  for (int s = 0; s < 16; ++s) {
    int rr = s * 2 + hi;
    short8 v8 = *(const short8*)(smem + w * 16384 + rr * 512 + lo * 16);
    int gc = (lo - rr) & 31;
    *(short8*)(Ob + (size_t)rr * Cn + gc * 8) = v8;
  }
}

// ---------------- proj GEMM + fused partial-combine + bias + residual --------
__global__ __launch_bounds__(256, 2)
void k_proj(const u16* __restrict__ wpb, const float* __restrict__ bp,
            const u16* __restrict__ O0, const u16* __restrict__ O1,
            const u16* __restrict__ O2, const u16* __restrict__ O3,
            const float* __restrict__ lrow, const float* __restrict__ x,
            float* __restrict__ out) {
  __shared__ __align__(16) char smem[65536];
  int tid = threadIdx.x, lane = tid & 63, w = tid >> 6, quad = lane >> 4, low = lane & 15;
  int n0 = blockIdx.x * 64, d0 = blockIdx.y * 64, b = blockIdx.z;
  {
    int r0 = w * 16;
#pragma unroll
    for (int s = 0; s < 8; ++s) {      // W tile via async DMA
      int rs = r0 + s * 2;
      int r = rs + (lane >> 5);
      int cb = (lane & 31) ^ (r & 7);
      gl_lds16(wpb + (size_t)(d0 + r) * Cn + cb * 8, smem + rs * 512);
    }
#pragma unroll
    for (int s = 0; s < 8; ++s) {      // B tile: combine 4 partials / l on the fly
      int rs = r0 + s * 2 + (lane >> 5);
      int cb = lane & 31;
      size_t rg = (size_t)b * Nn + n0 + rs;
      float L = lrow[rg] + lrow[(size_t)Bn * Nn + rg] +
                lrow[2 * (size_t)Bn * Nn + rg] + lrow[3 * (size_t)Bn * Nn + rg];
      float inv = __builtin_amdgcn_rcpf(L);
      size_t off = rg * Cn + cb * 8;
      short8 a0 = *(const short8*)(O0 + off);
      short8 a1 = *(const short8*)(O1 + off);
      short8 a2 = *(const short8*)(O2 + off);
      short8 a3 = *(const short8*)(O3 + off);
      short8 o;
#pragma unroll
      for (int e = 0; e < 8; ++e)
        o[e] = (short)f2bf((b2f((u16)a0[e]) + b2f((u16)a1[e]) +
                            b2f((u16)a2[e]) + b2f((u16)a3[e])) * inv);
      *(short8*)(smem + 32768 + rs * 512 + ((cb ^ (rs & 7)) * 16)) = o;
    }
  }
  asm volatile("s_waitcnt vmcnt(0)" ::: "memory");
  __syncthreads();
  f32x4 acc[4] = {{0.f,0.f,0.f,0.f},{0.f,0.f,0.f,0.f},{0.f,0.f,0.f,0.f},{0.f,0.f,0.f,0.f}};
#pragma unroll
  for (int kk = 0; kk < 8; ++kk) {
    short8 af = *(const short8*)(smem + sw512(w * 16 + low, kk * 4 + quad));
#pragma unroll
    for (int t = 0; t < 4; ++t) {
      short8 bf = *(const short8*)(smem + 32768 + sw512(t * 16 + low, kk * 4 + quad));
      acc[t] = __builtin_amdgcn_mfma_f32_16x16x32_bf16(af, bf, acc[t], 0, 0, 0);
    }
  }
  int dloc = d0 + w * 16 + quad * 4;
#pragma unroll
  for (int t = 0; t < 4; ++t)
#pragma unroll
    for (int r = 0; r < 4; ++r) {
      size_t idx = (size_t)b * Cn * Nn + (size_t)(dloc + r) * Nn + n0 + t * 16 + low;
      out[idx] = x[idx] + acc[t][r] + bp[dloc + r];
    }
}

// ---------------- launcher ----------------------------------------------------
extern "C" void kernel_launch(void* const* d_in, const int* in_sizes, int n_in,
                              void* d_out, int out_size, void* d_ws, size_t ws_size,
                              hipStream_t stream) {
  const float* x   = (const float*)d_in[0];
  const float* gsc = (const float*)d_in[1];
  const float* gbi = (const float*)d_in[2];
  const float* wq  = (const float*)d_in[3];
  const float* bq  = (const float*)d_in[4];
  const float* wk  = (const float*)d_in[5];
  const float* bk  = (const float*)d_in[6];
  const float* wv  = (const float*)d_in[7];
  const float* bv  = (const float*)d_in[8];
  const float* wp  = (const float*)d_in[9];
  const float* bp  = (const float*)d_in[10];
  float* out = (float*)d_out;

  char* ws = (char*)d_ws;
  u16*   wqkv  = (u16*)(ws + 0);          // 384 KB
  u16*   wpb   = (u16*)(ws + 393216);     // 128 KB
  float* bqkv  = (float*)(ws + 524288);   // 3 KB
  float* stats = (float*)(ws + 527360);   // 128*4*2 f32 = 4 KB (per-part slots)
  float* lrow  = (float*)(ws + 532480);   // 256 KB
  u16*   hnT   = (u16*)(ws + 1048576);    // 8 MB; reused as Op0 after qkv
  u16*   qT    = (u16*)(ws + 9437184);    // 8 MB
  u16*   kT    = (u16*)(ws + 17825792);   // 8 MB
  u16*   vv    = (u16*)(ws + 26214400);   // 8 MB
  u16*   Op1   = (u16*)(ws + 34603008);   // 8 MB
  u16*   Op2   = (u16*)(ws + 42991616);   // 8 MB
  u16*   Op3   = (u16*)(ws + 51380224);   // 8 MB; end ~57 MB

  k_cs<<<768, 256, 0, stream>>>(wq, wk, wv, wp, bq, bk, bv, x, wqkv, wpb, bqkv, stats);
  k_apply<<<dim3(64, 4), 256, 0, stream>>>(x, stats, gsc, gbi, hnT);
  k_qkv<<<dim3(64, 12, 4), 256, 0, stream>>>(wqkv, bqkv, hnT, qT, kT, vv);
  k_flash<<<dim3(32, 4, 4), 256, 0, stream>>>(qT, kT, vv, hnT /*Op0*/, Op1, Op2, Op3, lrow);
  k_proj<<<dim3(64, 4, 4), 256, 0, stream>>>(wpb, bp, hnT, Op1, Op2, Op3, lrow, x, out);
}

// Round 6
// 202.518 us; speedup vs baseline: 1.7206x; 1.0164x over previous
//
#include <hip/hip_runtime.h>
#include <stdint.h>

#define Bn 4
#define Cn 256
#define Gn 32
#define Nn 4096
#define CGn 8

typedef unsigned short u16;
typedef __attribute__((ext_vector_type(8))) short short8;
typedef __attribute__((ext_vector_type(4))) short short4v;
typedef __attribute__((ext_vector_type(4))) float f32x4;
typedef __attribute__((ext_vector_type(16))) float f32x16;

__device__ __forceinline__ u16 f2bf(float x) {
  uint32_t u = __float_as_uint(x);
  u += 0x7fffu + ((u >> 16) & 1u);
  return (u16)(u >> 16);
}
__device__ __forceinline__ float b2f(u16 v) {
  return __uint_as_float(((uint32_t)v) << 16);
}

// async global->LDS, 16B per lane; lds base must be wave-uniform
__device__ __forceinline__ void gl_lds16(const void* g, void* l) {
  __builtin_amdgcn_global_load_lds(
      (__attribute__((address_space(1))) void*)(uintptr_t)g,
      (__attribute__((address_space(3))) void*)(uintptr_t)l, 16, 0, 0);
}

// XOR-swizzled tile addressing (qkv/proj GEMMs): rows of 512B (32 x 16B chunks)
__device__ __forceinline__ int sw512(int row, int cb) { return row * 512 + ((cb ^ (row & 7)) * 16); }

// ---------------- fused weight-convert + GN stats ----------------------------
__global__ void k_cs(const float* __restrict__ wq, const float* __restrict__ wk,
                     const float* __restrict__ wv, const float* __restrict__ wp,
                     const float* __restrict__ bq, const float* __restrict__ bk,
                     const float* __restrict__ bv, const float* __restrict__ x,
                     u16* __restrict__ wqkv, u16* __restrict__ wpb,
                     float* __restrict__ bqkv, float* __restrict__ stats) {
  if (blockIdx.x < 256) {
    const float s = 0.09016844005556021f;  // log2(e) / sqrt(256)
    int i = blockIdx.x * 256 + threadIdx.x;
    wqkv[i]          = f2bf(wq[i] * s);
    wqkv[i + 65536]  = f2bf(wk[i]);
    wqkv[i + 131072] = f2bf(wv[i]);
    wpb[i]           = f2bf(wp[i]);
    if (i < 256) { bqkv[i] = bq[i] * s; bqkv[i + 256] = bk[i]; bqkv[i + 512] = bv[i]; }
  } else {
    int blk = blockIdx.x - 256;     // (b*32+g)*4 + part
    int grp = blk >> 2, part = blk & 3;
    const float4* base = (const float4*)(x + (size_t)grp * (CGn * Nn) + part * 8192);
    float s = 0.f, s2 = 0.f;
    for (int i = threadIdx.x; i < 2048; i += 256) {
      float4 v = base[i];
      s  += v.x + v.y + v.z + v.w;
      s2 += v.x * v.x + v.y * v.y + v.z * v.z + v.w * v.w;
    }
#pragma unroll
    for (int m = 1; m < 64; m <<= 1) { s += __shfl_xor(s, m, 64); s2 += __shfl_xor(s2, m, 64); }
    __shared__ float ps[4], ps2[4];
    int w = threadIdx.x >> 6;
    if ((threadIdx.x & 63) == 0) { ps[w] = s; ps2[w] = s2; }
    __syncthreads();
    if (threadIdx.x == 0) {
      stats[grp * 8 + part * 2]     = ps[0] + ps[1] + ps[2] + ps[3];
      stats[grp * 8 + part * 2 + 1] = ps2[0] + ps2[1] + ps2[2] + ps2[3];
    }
  }
}

// ---------------- GN apply -> hnT (N,C) bf16, coalesced via LDS transpose ----
__global__ void k_apply(const float* __restrict__ x, const float* __restrict__ stats,
                        const float* __restrict__ gsc, const float* __restrict__ gbi,
                        u16* __restrict__ hnT) {
  __shared__ __align__(16) char smem[32768];  // 64 n-rows x 512B (c), rotated
  __shared__ float smu[Gn], srs[Gn];
  int n0 = blockIdx.x * 64;
  int b = blockIdx.y;
  int tid = threadIdx.x;
  if (tid < Gn) {
    float S = 0.f, S2 = 0.f;
#pragma unroll
    for (int p = 0; p < 4; ++p) {
      S  += stats[(b * Gn + tid) * 8 + p * 2];
      S2 += stats[(b * Gn + tid) * 8 + p * 2 + 1];
    }
    const float inv = 1.f / (CGn * Nn);
    float mu = S * inv;
    float var = S2 * inv - mu * mu;
    smu[tid] = mu;
    srs[tid] = rsqrtf(var + 1e-6f);
  }
  __syncthreads();
  int nl = (tid & 15) * 4;
  int cbase = tid >> 4;
  for (int pass = 0; pass < 16; ++pass) {
    int c = pass * 16 + cbase;
    float4 v = *(const float4*)(x + (size_t)b * Cn * Nn + (size_t)c * Nn + n0 + nl);
    int g = c >> 3;
    float sc = gsc[c] * srs[g];
    float bi = gbi[c] - smu[g] * sc;
    float vals[4] = {v.x, v.y, v.z, v.w};
#pragma unroll
    for (int i = 0; i < 4; ++i) {
      int row = nl + i;
      int off = row * 512 + ((((c >> 3) + row) & 31) * 16) + (c & 7) * 2;
      *(u16*)(smem + off) = f2bf(vals[i] * sc + bi);
    }
  }
  __syncthreads();
#pragma unroll
  for (int p = 0; p < 8; ++p) {
    int idx = p * 256 + tid;   // 2048 chunk-slots
    int row = idx >> 5, pc = idx & 31;
    int gc = (pc - row) & 31;
    short8 v8 = *(const short8*)(smem + row * 512 + pc * 16);
    *(short8*)(hnT + ((size_t)b * Nn + n0 + row) * Cn + gc * 8) = v8;
  }
}

// ---------------- fused QKV GEMM: out[d,n] = sum_c W[d,c] hn[c,n] + bias ------
__global__ __launch_bounds__(256, 2)
void k_qkv(const u16* __restrict__ wqkv, const float* __restrict__ bqkv,
           const u16* __restrict__ hnT, u16* __restrict__ qT, u16* __restrict__ kT,
           u16* __restrict__ vv) {
  __shared__ __align__(16) char smem[65536];  // Ws [64][512B sw] | hns [64][512B sw]
  int tid = threadIdx.x, lane = tid & 63, w = tid >> 6, quad = lane >> 4, low = lane & 15;
  int n0 = blockIdx.x * 64, d0 = blockIdx.y * 64, b = blockIdx.z;
  {
    int r0 = w * 16;
#pragma unroll
    for (int s = 0; s < 8; ++s) {
      int rs = r0 + s * 2;
      int r = rs + (lane >> 5);
      int cb = (lane & 31) ^ (r & 7);
      gl_lds16(wqkv + (size_t)(d0 + r) * Cn + cb * 8, smem + rs * 512);
      gl_lds16(hnT + ((size_t)b * Nn + n0 + r) * Cn + cb * 8, smem + 32768 + rs * 512);
    }
  }
  asm volatile("s_waitcnt vmcnt(0)" ::: "memory");
  __syncthreads();
  f32x4 acc[4] = {{0.f,0.f,0.f,0.f},{0.f,0.f,0.f,0.f},{0.f,0.f,0.f,0.f},{0.f,0.f,0.f,0.f}};
#pragma unroll
  for (int kk = 0; kk < 8; ++kk) {
    short8 af = *(const short8*)(smem + sw512(w * 16 + low, kk * 4 + quad));
#pragma unroll
    for (int t = 0; t < 4; ++t) {
      short8 bf = *(const short8*)(smem + 32768 + sw512(t * 16 + low, kk * 4 + quad));
      acc[t] = __builtin_amdgcn_mfma_f32_16x16x32_bf16(af, bf, acc[t], 0, 0, 0);
    }
  }
  int which = d0 >> 8;
  float bias[4];
#pragma unroll
  for (int r = 0; r < 4; ++r) bias[r] = bqkv[d0 + w * 16 + quad * 4 + r];
  __syncthreads();  // all waves done reading GEMM tiles; reuse smem[0..8K)
  if (which == 2) {
#pragma unroll
    for (int t = 0; t < 4; ++t)
#pragma unroll
      for (int r = 0; r < 4; ++r) {
        int row = w * 16 + quad * 4 + r;   // d_local
        int col = t * 16 + low;            // n_local
        int off = row * 128 + ((((col >> 3) ^ ((row >> 1) & 7)) & 7) * 16) + (col & 7) * 2;
        *(u16*)(smem + off) = f2bf(acc[t][r] + bias[r]);
      }
  } else {
#pragma unroll
    for (int t = 0; t < 4; ++t)
#pragma unroll
      for (int r = 0; r < 4; ++r) {
        int row = t * 16 + low;            // n_local
        int col = w * 16 + quad * 4 + r;   // d_local
        int off = row * 128 + ((((col >> 3) ^ ((row >> 1) & 7)) & 7) * 16) + (col & 7) * 2;
        *(u16*)(smem + off) = f2bf(acc[t][r] + bias[r]);
      }
  }
  __syncthreads();
  int dl0 = d0 & 255;
#pragma unroll
  for (int p = 0; p < 2; ++p) {
    int idx = p * 256 + tid;       // [0,512) chunk-slots
    int row = idx >> 3, pc = idx & 7;
    int cb = pc ^ ((row >> 1) & 7);
    short8 v8 = *(const short8*)(smem + row * 128 + pc * 16);
    if (which == 2)
      *(short8*)(vv + (size_t)b * Cn * Nn + (size_t)(dl0 + row) * Nn + n0 + cb * 8) = v8;
    else {
      u16* dst = (which == 0 ? qT : kT) + (size_t)b * Nn * Cn;
      *(short8*)(dst + (size_t)(n0 + row) * Cn + dl0 + cb * 8) = v8;
    }
  }
}

// ---------------- flash attention, pipelined double-buffered K-loop ----------
// vs rotation rot(c)=c+(c>>2): per-phase bank-groups {0,5,2,7,1,6,3,4} distinct
// (period 8 in lane), vs the R5 rot(c)=c whose period-4 pattern 2-way conflicted
// every vs ds_read_b128.
__device__ __forceinline__ void flash_stage(char* smem, int bsel, const u16* kTb,
                                            const u16* vb, int j0, int w, int lo,
                                            int kr, int vr, int vp) {
  char* ksb = smem + bsel * 32768;
  char* vsb = ksb + 16384;
#pragma unroll
  for (int s = 0; s < 4; ++s) {   // ks: 32 rows x 512B, row-rotated chunks
    int j = kr + s * 2;
    int gc = (lo - j) & 31;
    gl_lds16(kTb + (size_t)(j0 + j) * Cn + gc * 8, ksb + (w * 8 + s * 2) * 512);
  }
#pragma unroll
  for (int s = 0; s < 4; ++s) {   // vs: 256 rows x 64B, rot(c)=c+(c>>2)
    int c = vr + s * 16;
    int gc = (vp - c - (c >> 2)) & 3;
    gl_lds16(vb + (size_t)c * Nn + j0 + gc * 8, vsb + (w * 64 + s * 16) * 64);
  }
}

__global__ __launch_bounds__(256, 2)
void k_flash(const u16* __restrict__ qT, const u16* __restrict__ kT,
             const u16* __restrict__ vv, u16* __restrict__ Op0,
             u16* __restrict__ Op1, u16* __restrict__ Op2, u16* __restrict__ Op3,
             float* __restrict__ lrow) {
  __shared__ __align__(16) char smem[65536];
  const int tid = threadIdx.x, lane = tid & 63, w = tid >> 6;
  const int lo = lane & 31, hi = lane >> 5;
  const int i0 = blockIdx.x * 128;
  const int b = blockIdx.y, jh = blockIdx.z;
  const u16* qTb = qT + (size_t)b * Nn * Cn;
  const u16* kTb = kT + (size_t)b * Nn * Cn;
  const u16* vb  = vv + (size_t)b * Cn * Nn;
  const int u7 = lo + hi;
  const int u9 = lo + hi + (lo >> 2);   // vs read rotation
  const int kr = w * 8 + hi;
  const int vr = w * 64 + (lane >> 2);
  const int vp = lane & 3;

  flash_stage(smem, 0, kTb, vb, jh * 1024, w, lo, kr, vr, vp);

  // q B-frags: lane holds q[i = i0+w*32+lo][c = ks*16 + hi*8 + e]
  short8 qf[16];
  {
    const u16* qrow = qTb + (size_t)(i0 + w * 32 + lo) * Cn + hi * 8;
#pragma unroll
    for (int ks = 0; ks < 16; ++ks) qf[ks] = *(const short8*)(qrow + ks * 16);
  }
  f32x16 Oa[8];
#pragma unroll
  for (int ct = 0; ct < 8; ++ct)
#pragma unroll
    for (int e = 0; e < 16; ++e) Oa[ct][e] = 0.f;
  float l_ = 0.f;

  for (int jt = 0; jt < 32; ++jt) {
    if (jt < 31) {
      flash_stage(smem, (jt + 1) & 1, kTb, vb, jh * 1024 + (jt + 1) * 32, w, lo, kr, vr, vp);
      asm volatile("s_waitcnt vmcnt(8)" ::: "memory");   // only the older 8 (current tile)
    } else {
      asm volatile("s_waitcnt vmcnt(0)" ::: "memory");
    }
    asm volatile("s_barrier" ::: "memory");              // raw: no vmcnt(0) drain
    const char* ksb = smem + (jt & 1) * 32768;
    const char* vsb = ksb + 16384;

    // S^T = K·q : D[m=j 32][n=i 32], A = ks (rotated), B = qf
    f32x16 S0;
#pragma unroll
    for (int e = 0; e < 16; ++e) S0[e] = 0.f;
#pragma unroll
    for (int ks = 0; ks < 16; ++ks) {
      int ch = (ks * 2 + u7) & 31;
      short8 a0 = *(const short8*)(ksb + lo * 512 + ch * 16);
      S0 = __builtin_amdgcn_mfma_f32_32x32x16_bf16(a0, qf[ks], S0, 0, 0, 0);
    }
    // P = exp2(S), pack bf16 pairs, per-lane l
    uint32_t Pp[8];
#pragma unroll
    for (int g = 0; g < 8; ++g) {
      float p0 = __builtin_amdgcn_exp2f(S0[2 * g]);
      float p1 = __builtin_amdgcn_exp2f(S0[2 * g + 1]);
      l_ += p0 + p1;
      Pp[g] = ((uint32_t)f2bf(p1) << 16) | f2bf(p0);
    }
    // PV: O^T[m=c][n=i] += V·P ; P B-frag via half-lane exchange
#pragma unroll
    for (int kst = 0; kst < 2; ++kst) {
      uint32_t a0 = Pp[4 * kst], a1 = Pp[4 * kst + 1];
      uint32_t b0 = Pp[4 * kst + 2], b1 = Pp[4 * kst + 3];
      uint32_t s0 = hi ? a0 : b0, s1 = hi ? a1 : b1;
      uint32_t r0 = (uint32_t)__shfl_xor((int)s0, 32, 64);
      uint32_t r1 = (uint32_t)__shfl_xor((int)s1, 32, 64);
      union { uint32_t u[4]; short8 s8; } pu;
      pu.u[0] = hi ? r0 : a0;
      pu.u[1] = hi ? r1 : a1;
      pu.u[2] = hi ? b0 : r0;
      pu.u[3] = hi ? b1 : r1;
      int ch = (kst * 2 + u9) & 3;
#pragma unroll
      for (int ct = 0; ct < 8; ++ct) {
        short8 vf = *(const short8*)(vsb + (ct * 32 + lo) * 64 + ch * 16);
        Oa[ct] = __builtin_amdgcn_mfma_f32_32x32x16_bf16(vf, pu.s8, Oa[ct], 0, 0, 0);
      }
    }
    asm volatile("s_barrier" ::: "memory");              // readers done before restage
  }

  // l: lane pair holds complementary j halves
  l_ += __shfl_xor(l_, 32, 64);
  if (hi == 0)
    lrow[(size_t)jh * (Bn * Nn) + (size_t)b * Nn + i0 + w * 32 + lo] = l_;
  float invl = __builtin_amdgcn_rcpf(l_);
  __syncthreads();  // loop drained (vmcnt(0) at last iter); reuse all 64KB
#pragma unroll
  for (int ct = 0; ct < 8; ++ct)
#pragma unroll
    for (int g = 0; g < 4; ++g) {
      short4v pk;
#pragma unroll
      for (int r = 0; r < 4; ++r) pk[r] = (short)f2bf(Oa[ct][g * 4 + r] * invl);
      int chv = (ct * 4 + g + lo) & 31;
      *(short4v*)(smem + w * 16384 + lo * 512 + chv * 16 + hi * 8) = pk;
    }
  __syncthreads();
  u16* Opj = (jh == 0) ? Op0 : (jh == 1) ? Op1 : (jh == 2) ? Op2 : Op3;
  u16* Ob = Opj + ((size_t)b * Nn + i0 + w * 32) * (size_t)Cn;
#pragma unroll
  for (int s = 0; s < 16; ++s) {
    int rr = s * 2 + hi;
    short8 v8 = *(const short8*)(smem + w * 16384 + rr * 512 + lo * 16);
    int gc = (lo - rr) & 31;
    *(short8*)(Ob + (size_t)rr * Cn + gc * 8) = v8;
  }
}

// ---------------- combine the 4 KV partials -> OT (N,C) bf16 -----------------
__global__ void k_comb(const u16* __restrict__ O0, const u16* __restrict__ O1,
                       const u16* __restrict__ O2, const u16* __restrict__ O3,
                       const float* __restrict__ lrow, u16* __restrict__ OT) {
  int gid = blockIdx.x * 256 + threadIdx.x;  // 1M threads, 4 cols each
  int row = gid >> 6;
  int c4 = (gid & 63) << 2;
  float L = lrow[row] + lrow[Bn * Nn + row] + lrow[2 * Bn * Nn + row] + lrow[3 * Bn * Nn + row];
  float inv = __builtin_amdgcn_rcpf(L);
  size_t base = (size_t)row * Cn + c4;
  short4v a0 = *(const short4v*)(O0 + base);
  short4v a1 = *(const short4v*)(O1 + base);
  short4v a2 = *(const short4v*)(O2 + base);
  short4v a3 = *(const short4v*)(O3 + base);
  short4v o;
#pragma unroll
  for (int i = 0; i < 4; ++i)
    o[i] = (short)f2bf((b2f((u16)a0[i]) + b2f((u16)a1[i]) + b2f((u16)a2[i]) + b2f((u16)a3[i])) * inv);
  *(short4v*)(OT + base) = o;
}

// ---------------- proj GEMM + bias + residual --------------------------------
__global__ __launch_bounds__(256, 2)
void k_proj(const u16* __restrict__ wpb, const float* __restrict__ bp,
            const u16* __restrict__ OT, const float* __restrict__ x,
            float* __restrict__ out) {
  __shared__ __align__(16) char smem[65536];
  int tid = threadIdx.x, lane = tid & 63, w = tid >> 6, quad = lane >> 4, low = lane & 15;
  int n0 = blockIdx.x * 64, d0 = blockIdx.y * 64, b = blockIdx.z;
  {
    int r0 = w * 16;
#pragma unroll
    for (int s = 0; s < 8; ++s) {
      int rs = r0 + s * 2;
      int r = rs + (lane >> 5);
      int cb = (lane & 31) ^ (r & 7);
      gl_lds16(wpb + (size_t)(d0 + r) * Cn + cb * 8, smem + rs * 512);
      gl_lds16(OT + ((size_t)b * Nn + n0 + r) * Cn + cb * 8, smem + 32768 + rs * 512);
    }
  }
  asm volatile("s_waitcnt vmcnt(0)" ::: "memory");
  __syncthreads();
  f32x4 acc[4] = {{0.f,0.f,0.f,0.f},{0.f,0.f,0.f,0.f},{0.f,0.f,0.f,0.f},{0.f,0.f,0.f,0.f}};
#pragma unroll
  for (int kk = 0; kk < 8; ++kk) {
    short8 af = *(const short8*)(smem + sw512(w * 16 + low, kk * 4 + quad));
#pragma unroll
    for (int t = 0; t < 4; ++t) {
      short8 bf = *(const short8*)(smem + 32768 + sw512(t * 16 + low, kk * 4 + quad));
      acc[t] = __builtin_amdgcn_mfma_f32_16x16x32_bf16(af, bf, acc[t], 0, 0, 0);
    }
  }
  int dloc = d0 + w * 16 + quad * 4;
#pragma unroll
  for (int t = 0; t < 4; ++t)
#pragma unroll
    for (int r = 0; r < 4; ++r) {
      size_t idx = (size_t)b * Cn * Nn + (size_t)(dloc + r) * Nn + n0 + t * 16 + low;
      out[idx] = x[idx] + acc[t][r] + bp[dloc + r];
    }
}

// ---------------- launcher ----------------------------------------------------
extern "C" void kernel_launch(void* const* d_in, const int* in_sizes, int n_in,
                              void* d_out, int out_size, void* d_ws, size_t ws_size,
                              hipStream_t stream) {
  const float* x   = (const float*)d_in[0];
  const float* gsc = (const float*)d_in[1];
  const float* gbi = (const float*)d_in[2];
  const float* wq  = (const float*)d_in[3];
  const float* bq  = (const float*)d_in[4];
  const float* wk  = (const float*)d_in[5];
  const float* bk  = (const float*)d_in[6];
  const float* wv  = (const float*)d_in[7];
  const float* bv  = (const float*)d_in[8];
  const float* wp  = (const float*)d_in[9];
  const float* bp  = (const float*)d_in[10];
  float* out = (float*)d_out;

  char* ws = (char*)d_ws;
  u16*   wqkv  = (u16*)(ws + 0);          // 384 KB
  u16*   wpb   = (u16*)(ws + 393216);     // 128 KB
  float* bqkv  = (float*)(ws + 524288);   // 3 KB
  float* stats = (float*)(ws + 527360);   // 4 KB (per-part slots)
  float* lrow  = (float*)(ws + 532480);   // 256 KB
  u16*   hnT   = (u16*)(ws + 1048576);    // 8 MB; reused as Op0 after qkv
  u16*   qT    = (u16*)(ws + 9437184);    // 8 MB; reused as OT after flash
  u16*   kT    = (u16*)(ws + 17825792);   // 8 MB
  u16*   vv    = (u16*)(ws + 26214400);   // 8 MB
  u16*   Op1   = (u16*)(ws + 34603008);   // 8 MB
  u16*   Op2   = (u16*)(ws + 42991616);   // 8 MB
  u16*   Op3   = (u16*)(ws + 51380224);   // 8 MB; end ~57 MB

  k_cs<<<768, 256, 0, stream>>>(wq, wk, wv, wp, bq, bk, bv, x, wqkv, wpb, bqkv, stats);
  k_apply<<<dim3(64, 4), 256, 0, stream>>>(x, stats, gsc, gbi, hnT);
  k_qkv<<<dim3(64, 12, 4), 256, 0, stream>>>(wqkv, bqkv, hnT, qT, kT, vv);
  k_flash<<<dim3(32, 4, 4), 256, 0, stream>>>(qT, kT, vv, hnT /*Op0*/, Op1, Op2, Op3, lrow);
  k_comb<<<4096, 256, 0, stream>>>(hnT, Op1, Op2, Op3, lrow, qT /*OT*/);
  k_proj<<<dim3(64, 4, 4), 256, 0, stream>>>(wpb, bp, qT /*OT*/, x, out);
}